// Round 1
// baseline (931.787 us; speedup 1.0000x reference)
//
#include <hip/hip_runtime.h>
#include <stdint.h>

typedef __bf16 bf16x8 __attribute__((ext_vector_type(8)));
typedef __bf16 bf16x4 __attribute__((ext_vector_type(4)));
typedef float  floatx4 __attribute__((ext_vector_type(4)));

#define B_  16
#define LQ  2048
#define LV  2048
#define DD  512

// async global->LDS, 16B per lane; LDS dest = wave-uniform base + lane*16
__device__ __forceinline__ void gl_lds16(const void* g, void* l) {
  __builtin_amdgcn_global_load_lds(
      (const __attribute__((address_space(1))) unsigned int*)g,
      (__attribute__((address_space(3))) unsigned int*)l, 16, 0, 0);
}

// ---------- K0a: split fp32 -> (hi, lo) bf16 for Q and V ----------
__global__ __launch_bounds__(256) void cvt_split(
    const float* __restrict__ Q, const float* __restrict__ V,
    __bf16* __restrict__ qh, __bf16* __restrict__ ql,
    __bf16* __restrict__ vh, __bf16* __restrict__ vl) {
  size_t i = ((size_t)blockIdx.x * 256 + threadIdx.x) * 4;
  float4 q = *(const float4*)(Q + i);
  float4 v = *(const float4*)(V + i);
  float qa[4] = {q.x, q.y, q.z, q.w};
  float va[4] = {v.x, v.y, v.z, v.w};
  bf16x4 qhi, qlo, vhi, vlo;
#pragma unroll
  for (int j = 0; j < 4; j++) {
    __bf16 h = (__bf16)qa[j]; qhi[j] = h; qlo[j] = (__bf16)(qa[j] - (float)h);
    __bf16 g = (__bf16)va[j]; vhi[j] = g; vlo[j] = (__bf16)(va[j] - (float)g);
  }
  *(bf16x4*)(qh + i) = qhi; *(bf16x4*)(ql + i) = qlo;
  *(bf16x4*)(vh + i) = vhi; *(bf16x4*)(vl + i) = vlo;
}

// ---------- K0b: V [Lv][D] fp32 -> Vt [D][Lv] bf16 (hi only) ----------
__global__ __launch_bounds__(256) void transp_v(const float* __restrict__ V,
                                                __bf16* __restrict__ vt) {
  __shared__ float tile[32][33];
  int b = blockIdx.z;
  int v0 = blockIdx.x * 32, d0 = blockIdx.y * 32;
  int t = threadIdx.x, r = t >> 3, c4 = (t & 7) * 4;
  const float* Vb = V + (size_t)b * LV * DD;
  float4 x = *(const float4*)(Vb + (size_t)(v0 + r) * DD + d0 + c4);
  tile[r][c4] = x.x; tile[r][c4 + 1] = x.y; tile[r][c4 + 2] = x.z; tile[r][c4 + 3] = x.w;
  __syncthreads();
  bf16x4 o;
#pragma unroll
  for (int j = 0; j < 4; j++) o[j] = (__bf16)tile[c4 + j][r];
  *(bf16x4*)(vt + (size_t)b * DD * LV + (size_t)(d0 + r) * LV + v0 + c4) = o;
}

// ---------- K1: S = Q V^T via split-bf16 (3 MFMA terms), 128x128 tile ----------
__global__ __launch_bounds__(256) void gemm1_scores(
    const __bf16* __restrict__ qh, const __bf16* __restrict__ ql,
    const __bf16* __restrict__ vh, const __bf16* __restrict__ vl,
    float* __restrict__ S) {
  __shared__ __attribute__((aligned(16))) __bf16 Ah[128 * 32], Al[128 * 32];
  __shared__ __attribute__((aligned(16))) __bf16 Bh[128 * 32], Bl[128 * 32];
  int b = blockIdx.z, mt = blockIdx.y, nt = blockIdx.x;
  int t = threadIdx.x, w = t >> 6, l = t & 63;
  int wm = w >> 1, wn = w & 1;          // 2x2 wave grid, 64x64 each
  int lr = l & 15, kg = l >> 4;         // frag row/col, k-group
  const __bf16* qhb = qh + (size_t)b * LQ * DD + (size_t)(mt * 128) * DD;
  const __bf16* qlb = ql + (size_t)b * LQ * DD + (size_t)(mt * 128) * DD;
  const __bf16* vhb = vh + (size_t)b * LV * DD + (size_t)(nt * 128) * DD;
  const __bf16* vlb = vl + (size_t)b * LV * DD + (size_t)(nt * 128) * DD;
  int spart = t & 3;
  floatx4 acc[16] = {};
  for (int k0 = 0; k0 < DD; k0 += 32) {
#pragma unroll
    for (int i = 0; i < 2; i++) {       // 8KB per array, 2 issues of 4KB
      int row = i * 64 + (t >> 2);
      size_t goff = (size_t)row * DD + k0 + spart * 8;
      int loff = (i * 256 + w * 64) * 8;
      gl_lds16(qhb + goff, Ah + loff);
      gl_lds16(qlb + goff, Al + loff);
      gl_lds16(vhb + goff, Bh + loff);
      gl_lds16(vlb + goff, Bl + loff);
    }
    __syncthreads();
    bf16x8 ah[4], al[4], bh[4], bl[4];
#pragma unroll
    for (int mi = 0; mi < 4; mi++) {
      int off = (wm * 64 + mi * 16 + lr) * 32 + kg * 8;
      ah[mi] = *(const bf16x8*)&Ah[off];
      al[mi] = *(const bf16x8*)&Al[off];
    }
#pragma unroll
    for (int ni = 0; ni < 4; ni++) {
      int off = (wn * 64 + ni * 16 + lr) * 32 + kg * 8;
      bh[ni] = *(const bf16x8*)&Bh[off];
      bl[ni] = *(const bf16x8*)&Bl[off];
    }
#pragma unroll
    for (int mi = 0; mi < 4; mi++)
#pragma unroll
      for (int ni = 0; ni < 4; ni++) {
        floatx4 c = acc[mi * 4 + ni];
        c = __builtin_amdgcn_mfma_f32_16x16x32_bf16(ah[mi], bh[ni], c, 0, 0, 0);
        c = __builtin_amdgcn_mfma_f32_16x16x32_bf16(ah[mi], bl[ni], c, 0, 0, 0);
        c = __builtin_amdgcn_mfma_f32_16x16x32_bf16(al[mi], bh[ni], c, 0, 0, 0);
        acc[mi * 4 + ni] = c;
      }
    __syncthreads();
  }
  // C/D layout 16x16: col = lane&15, row = (lane>>4)*4 + reg
  float* Sb = S + (size_t)b * LQ * LV + (size_t)(mt * 128 + wm * 64) * LV + (nt * 128 + wn * 64);
#pragma unroll
  for (int mi = 0; mi < 4; mi++)
#pragma unroll
    for (int ni = 0; ni < 4; ni++)
#pragma unroll
      for (int r = 0; r < 4; r++)
        Sb[(size_t)(mi * 16 + kg * 4 + r) * LV + ni * 16 + lr] = acc[mi * 4 + ni][r];
}

// ---------- K2: per-row max and 1/sum(exp) ----------
__global__ __launch_bounds__(256) void rowstats(const float* __restrict__ S,
                                                float2* __restrict__ stats) {
  int r = blockIdx.x * 4 + (threadIdx.x >> 6);
  int l = threadIdx.x & 63;
  const float4* row = (const float4*)(S + (size_t)r * LV);
  float4 v[8];
#pragma unroll
  for (int i = 0; i < 8; i++) v[i] = row[i * 64 + l];
  float m = -3.0e38f;
#pragma unroll
  for (int i = 0; i < 8; i++)
    m = fmaxf(m, fmaxf(fmaxf(v[i].x, v[i].y), fmaxf(v[i].z, v[i].w)));
#pragma unroll
  for (int off = 32; off > 0; off >>= 1) m = fmaxf(m, __shfl_xor(m, off));
  float s = 0.f;
#pragma unroll
  for (int i = 0; i < 8; i++)
    s += __expf(v[i].x - m) + __expf(v[i].y - m) + __expf(v[i].z - m) + __expf(v[i].w - m);
#pragma unroll
  for (int off = 32; off > 0; off >>= 1) s += __shfl_xor(s, off);
  if (l == 0) stats[r] = make_float2(m, 1.0f / s);
}

// ---------- K3: attn = softmax(S) written in place; context = attn @ V ----------
__global__ __launch_bounds__(256) void gemm2_ctx(
    float* SA,                                    // scores in, attn out (in place)
    const __bf16* __restrict__ vt, const float2* __restrict__ stats,
    float* __restrict__ ctx) {
  __shared__ __attribute__((aligned(16))) __bf16 Ps[32 * 32];
  __shared__ __attribute__((aligned(16))) __bf16 Vts[512 * 32];
  int b = blockIdx.z, mb = blockIdx.x;
  int t = threadIdx.x, w = t >> 6, l = t & 63;
  int lr = l & 15, kg = l >> 4;
  int m0 = mb * 32;
  float* Sb = SA + ((size_t)b * LQ + m0) * LV;
  const __bf16* vtb = vt + (size_t)b * DD * LV;
  int srow = t >> 3, scol = (t & 7) * 4;
  float2 st = stats[b * LQ + m0 + srow];
  floatx4 acc[16] = {};
  for (int k0 = 0; k0 < LV; k0 += 32) {
#pragma unroll
    for (int i = 0; i < 8; i++) {                 // Vt tile [512][32] bf16 = 32KB
      int row = i * 64 + (t >> 2);
      gl_lds16(vtb + (size_t)row * LV + k0 + (t & 3) * 8, Vts + (i * 256 + w * 64) * 8);
    }
    float4 s4 = *(const float4*)(Sb + (size_t)srow * LV + k0 + scol);
    float4 p4;
    p4.x = __expf(s4.x - st.x) * st.y;
    p4.y = __expf(s4.y - st.x) * st.y;
    p4.z = __expf(s4.z - st.x) * st.y;
    p4.w = __expf(s4.w - st.x) * st.y;
    *(float4*)(Sb + (size_t)srow * LV + k0 + scol) = p4;   // attn write (in place)
    bf16x4 pb;
    pb[0] = (__bf16)p4.x; pb[1] = (__bf16)p4.y; pb[2] = (__bf16)p4.z; pb[3] = (__bf16)p4.w;
    *(bf16x4*)&Ps[srow * 32 + scol] = pb;
    __syncthreads();
    bf16x8 a0 = *(const bf16x8*)&Ps[lr * 32 + kg * 8];
    bf16x8 a1 = *(const bf16x8*)&Ps[(16 + lr) * 32 + kg * 8];
#pragma unroll
    for (int nf = 0; nf < 8; nf++) {
      bf16x8 bb = *(const bf16x8*)&Vts[(w * 128 + nf * 16 + lr) * 32 + kg * 8];
      acc[nf]     = __builtin_amdgcn_mfma_f32_16x16x32_bf16(a0, bb, acc[nf], 0, 0, 0);
      acc[8 + nf] = __builtin_amdgcn_mfma_f32_16x16x32_bf16(a1, bb, acc[8 + nf], 0, 0, 0);
    }
    __syncthreads();
  }
  float* Cb = ctx + ((size_t)b * LQ + m0) * DD + (size_t)(w * 128);
#pragma unroll
  for (int mi = 0; mi < 2; mi++)
#pragma unroll
    for (int nf = 0; nf < 8; nf++)
#pragma unroll
      for (int r = 0; r < 4; r++)
        Cb[(size_t)(mi * 16 + kg * 4 + r) * DD + nf * 16 + lr] = acc[mi * 8 + nf][r];
}

extern "C" void kernel_launch(void* const* d_in, const int* in_sizes, int n_in,
                              void* d_out, int out_size, void* d_ws, size_t ws_size,
                              hipStream_t stream) {
  const float* Q = (const float*)d_in[0];
  const float* V = (const float*)d_in[1];
  float* out = (float*)d_out;
  float* ctx = out;                          // [16][2048][512]
  float* SA  = out + (size_t)B_ * LQ * DD;   // [16][2048][2048]: scores, then attn
  char* wsp = (char*)d_ws;
  size_t nqv = (size_t)B_ * LQ * DD;         // 16,777,216 elements
  __bf16* qh = (__bf16*)wsp;
  __bf16* ql = (__bf16*)(wsp + nqv * 2);
  __bf16* vh = (__bf16*)(wsp + nqv * 4);
  __bf16* vl = (__bf16*)(wsp + nqv * 6);
  float2* stats = (float2*)(wsp + nqv * 8);  // 32768 * 8B
  __bf16* vt = qh;                           // reuse qh region after gemm1

  cvt_split<<<dim3((unsigned)(nqv / 1024)), 256, 0, stream>>>(Q, V, qh, ql, vh, vl);
  gemm1_scores<<<dim3(16, 16, B_), 256, 0, stream>>>(qh, ql, vh, vl, SA);
  rowstats<<<dim3(B_ * LQ / 4), 256, 0, stream>>>(SA, stats);
  transp_v<<<dim3(LV / 32, DD / 32, B_), 256, 0, stream>>>(V, vt);
  gemm2_ctx<<<dim3(LQ / 32, 1, B_), 256, 0, stream>>>(SA, vt, stats, ctx);
}

// Round 2
// 885.770 us; speedup vs baseline: 1.0520x; 1.0520x over previous
//
#include <hip/hip_runtime.h>
#include <stdint.h>

typedef __bf16 bf16x8 __attribute__((ext_vector_type(8)));
typedef __bf16 bf16x4 __attribute__((ext_vector_type(4)));
typedef float  floatx4 __attribute__((ext_vector_type(4)));

#define B_  16
#define LQ  2048
#define LV  2048
#define DD  512

// async global->LDS, 16B per lane; LDS dest = wave-uniform base + lane*16
__device__ __forceinline__ void gl_lds16(const void* g, void* l) {
  __builtin_amdgcn_global_load_lds(
      (const __attribute__((address_space(1))) unsigned int*)g,
      (__attribute__((address_space(3))) unsigned int*)l, 16, 0, 0);
}

// ---------- K0a: split fp32 -> (hi, lo) bf16 for Q and V, 8 elems/thread ----------
__global__ __launch_bounds__(256) void cvt_split(
    const float* __restrict__ Q, const float* __restrict__ V,
    __bf16* __restrict__ qh, __bf16* __restrict__ ql,
    __bf16* __restrict__ vh, __bf16* __restrict__ vl) {
  size_t i = ((size_t)blockIdx.x * 256 + threadIdx.x) * 8;
  float4 q0 = *(const float4*)(Q + i), q1 = *(const float4*)(Q + i + 4);
  float4 v0 = *(const float4*)(V + i), v1 = *(const float4*)(V + i + 4);
  float qa[8] = {q0.x, q0.y, q0.z, q0.w, q1.x, q1.y, q1.z, q1.w};
  float va[8] = {v0.x, v0.y, v0.z, v0.w, v1.x, v1.y, v1.z, v1.w};
  bf16x8 qhi, qlo, vhi, vlo;
#pragma unroll
  for (int j = 0; j < 8; j++) {
    __bf16 h = (__bf16)qa[j]; qhi[j] = h; qlo[j] = (__bf16)(qa[j] - (float)h);
    __bf16 g = (__bf16)va[j]; vhi[j] = g; vlo[j] = (__bf16)(va[j] - (float)g);
  }
  *(bf16x8*)(qh + i) = qhi; *(bf16x8*)(ql + i) = qlo;
  *(bf16x8*)(vh + i) = vhi; *(bf16x8*)(vl + i) = vlo;
}

// ---------- K0b: V [Lv][D] fp32 -> Vt [D][Lv] bf16 (hi only) ----------
__global__ __launch_bounds__(256) void transp_v(const float* __restrict__ V,
                                                __bf16* __restrict__ vt) {
  __shared__ float tile[32][33];
  int b = blockIdx.z;
  int v0 = blockIdx.x * 32, d0 = blockIdx.y * 32;
  int t = threadIdx.x, r = t >> 3, c4 = (t & 7) * 4;
  const float* Vb = V + (size_t)b * LV * DD;
  float4 x = *(const float4*)(Vb + (size_t)(v0 + r) * DD + d0 + c4);
  tile[r][c4] = x.x; tile[r][c4 + 1] = x.y; tile[r][c4 + 2] = x.z; tile[r][c4 + 3] = x.w;
  __syncthreads();
  bf16x4 o;
#pragma unroll
  for (int j = 0; j < 4; j++) o[j] = (__bf16)tile[c4 + j][r];
  *(bf16x4*)(vt + (size_t)b * DD * LV + (size_t)(d0 + r) * LV + v0 + c4) = o;
}

// ---------- K1: S = Q V^T via split-bf16 (3 MFMA terms), 128x128 tile ----------
// Also emits per-row partial (max, sumexp) over each wave's 64-col stripe -> pp.
__global__ __launch_bounds__(256) void gemm1_scores(
    const __bf16* __restrict__ qh, const __bf16* __restrict__ ql,
    const __bf16* __restrict__ vh, const __bf16* __restrict__ vl,
    float* __restrict__ S, float2* __restrict__ pp) {
  __shared__ __attribute__((aligned(16))) __bf16 Ah[128 * 32], Al[128 * 32];
  __shared__ __attribute__((aligned(16))) __bf16 Bh[128 * 32], Bl[128 * 32];
  int b = blockIdx.z, mt = blockIdx.y, nt = blockIdx.x;
  int t = threadIdx.x, w = t >> 6, l = t & 63;
  int wm = w >> 1, wn = w & 1;          // 2x2 wave grid, 64x64 each
  int lr = l & 15, kg = l >> 4;         // frag row/col, k-group
  const __bf16* qhb = qh + (size_t)b * LQ * DD + (size_t)(mt * 128) * DD;
  const __bf16* qlb = ql + (size_t)b * LQ * DD + (size_t)(mt * 128) * DD;
  const __bf16* vhb = vh + (size_t)b * LV * DD + (size_t)(nt * 128) * DD;
  const __bf16* vlb = vl + (size_t)b * LV * DD + (size_t)(nt * 128) * DD;
  int spart = t & 3;
  floatx4 acc[16] = {};
  for (int k0 = 0; k0 < DD; k0 += 32) {
#pragma unroll
    for (int i = 0; i < 2; i++) {       // 8KB per array, 2 issues of 4KB
      int row = i * 64 + (t >> 2);
      size_t goff = (size_t)row * DD + k0 + spart * 8;
      int loff = (i * 256 + w * 64) * 8;
      gl_lds16(qhb + goff, Ah + loff);
      gl_lds16(qlb + goff, Al + loff);
      gl_lds16(vhb + goff, Bh + loff);
      gl_lds16(vlb + goff, Bl + loff);
    }
    __syncthreads();
    bf16x8 ah[4], al[4], bh[4], bl[4];
#pragma unroll
    for (int mi = 0; mi < 4; mi++) {
      int off = (wm * 64 + mi * 16 + lr) * 32 + kg * 8;
      ah[mi] = *(const bf16x8*)&Ah[off];
      al[mi] = *(const bf16x8*)&Al[off];
    }
#pragma unroll
    for (int ni = 0; ni < 4; ni++) {
      int off = (wn * 64 + ni * 16 + lr) * 32 + kg * 8;
      bh[ni] = *(const bf16x8*)&Bh[off];
      bl[ni] = *(const bf16x8*)&Bl[off];
    }
#pragma unroll
    for (int mi = 0; mi < 4; mi++)
#pragma unroll
      for (int ni = 0; ni < 4; ni++) {
        floatx4 c = acc[mi * 4 + ni];
        c = __builtin_amdgcn_mfma_f32_16x16x32_bf16(ah[mi], bh[ni], c, 0, 0, 0);
        c = __builtin_amdgcn_mfma_f32_16x16x32_bf16(ah[mi], bl[ni], c, 0, 0, 0);
        c = __builtin_amdgcn_mfma_f32_16x16x32_bf16(al[mi], bh[ni], c, 0, 0, 0);
        acc[mi * 4 + ni] = c;
      }
    __syncthreads();
  }
  // C/D layout 16x16: col = lane&15, row = (lane>>4)*4 + reg
  float* Sb = S + (size_t)b * LQ * LV + (size_t)(mt * 128 + wm * 64) * LV + (nt * 128 + wn * 64);
#pragma unroll
  for (int mi = 0; mi < 4; mi++)
#pragma unroll
    for (int ni = 0; ni < 4; ni++)
#pragma unroll
      for (int r = 0; r < 4; r++)
        Sb[(size_t)(mi * 16 + kg * 4 + r) * LV + ni * 16 + lr] = acc[mi * 4 + ni][r];
  // per-row partial softmax stats over this wave's 64-col stripe
  int stripe = nt * 2 + wn;
  float2* pb = pp + ((size_t)b * LQ + mt * 128 + wm * 64) * 32;
#pragma unroll
  for (int mi = 0; mi < 4; mi++) {
    float pm[4], ps_[4];
#pragma unroll
    for (int r = 0; r < 4; r++) {
      float m = fmaxf(fmaxf(acc[mi * 4 + 0][r], acc[mi * 4 + 1][r]),
                      fmaxf(acc[mi * 4 + 2][r], acc[mi * 4 + 3][r]));
#pragma unroll
      for (int s = 1; s < 16; s <<= 1) m = fmaxf(m, __shfl_xor(m, s));
      float sm = 0.f;
#pragma unroll
      for (int ni = 0; ni < 4; ni++) sm += __expf(acc[mi * 4 + ni][r] - m);
#pragma unroll
      for (int s = 1; s < 16; s <<= 1) sm += __shfl_xor(sm, s);
      pm[r] = m; ps_[r] = sm;
    }
    if (lr == 0) {
#pragma unroll
      for (int r = 0; r < 4; r++)
        pb[(size_t)(mi * 16 + kg * 4 + r) * 32 + stripe] = make_float2(pm[r], ps_[r]);
    }
  }
}

// ---------- K2: fold 32 stripe-partials per row -> (max, 1/sum) ----------
__global__ __launch_bounds__(256) void combine_stats(const float2* __restrict__ pp,
                                                     float2* __restrict__ stats) {
  int r = blockIdx.x * 256 + threadIdx.x;   // 0..B*LQ-1
  const float2* p = pp + (size_t)r * 32;
  float2 v[32];
#pragma unroll
  for (int i = 0; i < 32; i++) v[i] = p[i];
  float m = -3.0e38f;
#pragma unroll
  for (int i = 0; i < 32; i++) m = fmaxf(m, v[i].x);
  float s = 0.f;
#pragma unroll
  for (int i = 0; i < 32; i++) s += v[i].y * __expf(v[i].x - m);
  stats[r] = make_float2(m, 1.0f / s);
}

// ---------- K3: attn = softmax(S) in place; ctx = attn @ V. M=64/block ----------
__global__ __launch_bounds__(256, 2) void gemm2_ctx(
    float* SA,                                    // scores in, attn out (in place)
    const __bf16* __restrict__ vt, const float2* __restrict__ stats,
    float* __restrict__ ctx) {
  __shared__ __attribute__((aligned(16))) __bf16 Ps[64 * 32];
  __shared__ __attribute__((aligned(16))) __bf16 Vts[512 * 32];
  int b = blockIdx.z, mb = blockIdx.x;
  int t = threadIdx.x, w = t >> 6, l = t & 63;
  int lr = l & 15, kg = l >> 4;
  int m0 = mb * 64;
  float* Sb = SA + ((size_t)b * LQ + m0) * LV;
  const __bf16* vtb = vt + (size_t)b * DD * LV;
  int srow = t >> 2, skcol = (t & 3) * 8;       // S-staging: 64 rows x 32 k
  float2 st = stats[b * LQ + m0 + srow];
  floatx4 acc[32] = {};
  for (int k0 = 0; k0 < LV; k0 += 32) {
#pragma unroll
    for (int i = 0; i < 8; i++) {               // Vt tile [512][32] bf16 = 32KB
      int slot = i * 256 + t;
      gl_lds16(vtb + (size_t)(slot >> 2) * LV + k0 + (slot & 3) * 8,
               Vts + (size_t)(i * 256 + w * 64) * 8);
    }
    float* sp = Sb + (size_t)srow * LV + k0 + skcol;
    float4 s0 = *(const float4*)sp, s1 = *(const float4*)(sp + 4);
    float p[8] = {s0.x, s0.y, s0.z, s0.w, s1.x, s1.y, s1.z, s1.w};
    bf16x8 pbv;
#pragma unroll
    for (int j = 0; j < 8; j++) { p[j] = __expf(p[j] - st.x) * st.y; pbv[j] = (__bf16)p[j]; }
    float4 o0 = {p[0], p[1], p[2], p[3]}, o1 = {p[4], p[5], p[6], p[7]};
    *(float4*)sp = o0; *(float4*)(sp + 4) = o1;   // attn write (in place)
    *(bf16x8*)&Ps[srow * 32 + skcol] = pbv;
    __syncthreads();
    bf16x8 a[4];
#pragma unroll
    for (int mi = 0; mi < 4; mi++) a[mi] = *(const bf16x8*)&Ps[(mi * 16 + lr) * 32 + kg * 8];
#pragma unroll
    for (int nf = 0; nf < 8; nf++) {
      bf16x8 bb = *(const bf16x8*)&Vts[(w * 128 + nf * 16 + lr) * 32 + kg * 8];
#pragma unroll
      for (int mi = 0; mi < 4; mi++)
        acc[mi * 8 + nf] = __builtin_amdgcn_mfma_f32_16x16x32_bf16(a[mi], bb, acc[mi * 8 + nf], 0, 0, 0);
    }
    __syncthreads();
  }
  float* Cb = ctx + ((size_t)b * LQ + m0) * DD + (size_t)(w * 128);
#pragma unroll
  for (int mi = 0; mi < 4; mi++)
#pragma unroll
    for (int nf = 0; nf < 8; nf++)
#pragma unroll
      for (int r = 0; r < 4; r++)
        Cb[(size_t)(mi * 16 + kg * 4 + r) * DD + nf * 16 + lr] = acc[mi * 8 + nf][r];
}

extern "C" void kernel_launch(void* const* d_in, const int* in_sizes, int n_in,
                              void* d_out, int out_size, void* d_ws, size_t ws_size,
                              hipStream_t stream) {
  const float* Q = (const float*)d_in[0];
  const float* V = (const float*)d_in[1];
  float* out = (float*)d_out;
  float* ctx = out;                          // [16][2048][512]
  float* SA  = out + (size_t)B_ * LQ * DD;   // [16][2048][2048]: scores, then attn
  float2* pp = (float2*)ctx;                 // stripe partials, 8MB, dead before ctx write
  char* wsp = (char*)d_ws;
  size_t nqv = (size_t)B_ * LQ * DD;         // 16,777,216 elements
  __bf16* qh = (__bf16*)wsp;
  __bf16* ql = (__bf16*)(wsp + nqv * 2);
  __bf16* vh = (__bf16*)(wsp + nqv * 4);
  __bf16* vl = (__bf16*)(wsp + nqv * 6);
  float2* stats = (float2*)(wsp + nqv * 8);  // 32768 * 8B
  __bf16* vt = qh;                           // reuse qh region after gemm1

  cvt_split<<<dim3((unsigned)(nqv / 2048)), 256, 0, stream>>>(Q, V, qh, ql, vh, vl);
  gemm1_scores<<<dim3(16, 16, B_), 256, 0, stream>>>(qh, ql, vh, vl, SA, pp);
  transp_v<<<dim3(LV / 32, DD / 32, B_), 256, 0, stream>>>(V, vt);
  combine_stats<<<dim3(B_ * LQ / 256), 256, 0, stream>>>(pp, stats);
  gemm2_ctx<<<dim3(LQ / 64, 1, B_), 256, 0, stream>>>(SA, vt, stats, ctx);
}